// Round 11
// baseline (163.431 us; speedup 1.0000x reference)
//
#include <hip/hip_runtime.h>
#include <hip/hip_bf16.h>
#include <math.h>

// Problem constants (B,F,H,E,O) = (512,512,512,8,512)
enum { Bq = 512, Fq = 512, Hq = 512, Eq = 8, Oq = 512 };

typedef __attribute__((ext_vector_type(8))) short short8;
typedef __attribute__((ext_vector_type(4))) float floatx4;

static __device__ __forceinline__ unsigned short f2bf(float f) {
  unsigned u = __float_as_uint(f);
  u += 0x7fffu + ((u >> 16) & 1u);
  return (unsigned short)(u >> 16);
}
static __device__ __forceinline__ float bf2f(unsigned short h) {
  return __uint_as_float(((unsigned)h) << 16);
}
static __device__ __forceinline__ float elu1(float v) {
  return v > 0.f ? v : (__expf(v) - 1.f);
}

// async global->LDS 16B copy (wave-uniform LDS base + lane*16 scatter)
typedef __attribute__((address_space(1))) const unsigned int gu32;
typedef __attribute__((address_space(3))) unsigned int lu32;
static __device__ __forceinline__ void gld16(const unsigned short* g,
                                             unsigned short* l) {
  __builtin_amdgcn_global_load_lds((gu32*)g, (lu32*)l, 16, 0, 0);
}

// XOR swizzle on 16B chunks (fragment-read conflicts -> 2-way = free).
static __device__ __forceinline__ int swz(int q, int r) {
  return (q & ~7) | ((q ^ r) & 7);
}

// one 256-thread block converts 256 float4 (1024 elems) fp32->bf16
static __device__ __forceinline__ void cvt_chunk(const float* __restrict__ src,
                                                 unsigned short* __restrict__ dst,
                                                 int chunk, int tid) {
  int j = chunk * 256 + tid;
  float4 v = ((const float4*)src)[j];
  ushort4 o;
  o.x = f2bf(v.x); o.y = f2bf(v.y); o.z = f2bf(v.z); o.w = f2bf(v.w);
  *(ushort4*)(dst + 4 * (size_t)j) = o;
}

// ---------------- small cvt: x, gw0 (256 chunk-blocks each) -----------------
__global__ __launch_bounds__(256) void cvt_small2(
    const float* __restrict__ s0, const float* __restrict__ s1,
    unsigned short* __restrict__ d0, unsigned short* __restrict__ d1) {
  int blk = blockIdx.x;
  if (blk < 256)
    cvt_chunk(s0, d0, blk, threadIdx.x);
  else
    cvt_chunk(s1, d1, blk - 256, threadIdx.x);
}

// --- gating GEMM (blocks 0..255) + alpha cvt (256..2303) + opt small cvt ----
__global__ __launch_bounds__(256) void gating_cvt(
    const unsigned short* __restrict__ A, const unsigned short* __restrict__ W,
    const float* __restrict__ bias, unsigned short* __restrict__ C,
    const float* __restrict__ asrc, unsigned short* __restrict__ adst,
    const float* __restrict__ ssrc, unsigned short* __restrict__ sdst) {
  const int blk = blockIdx.x, tid = threadIdx.x;
  if (blk >= 2304) {
    cvt_chunk(ssrc, sdst, blk - 2304, tid);
    return;
  }
  if (blk >= 256) {
    cvt_chunk(asrc, adst, blk - 256, tid);
    return;
  }
  __shared__ unsigned short As[32 * 512];
  __shared__ unsigned short Ws[32 * 512];
  const int wave = tid >> 6, lane = tid & 63;
  const int wm = wave >> 1, wn = wave & 1;
  const int lr = lane & 15, lk = lane >> 4;
  const int m0 = (blk >> 4) * 32, n0 = (blk & 15) * 32;
#pragma unroll
  for (int i = 0; i < 8; i++) {
    int c = tid + i * 256;
    int r = c >> 6, ql = c & 63;
    gld16(&A[(size_t)(m0 + r) * 512 + swz(ql, r) * 8], &As[(c & ~63) * 8]);
  }
#pragma unroll
  for (int i = 0; i < 8; i++) {
    int c = tid + i * 256;
    int r = c >> 6, ql = c & 63;
    gld16(&W[(size_t)(n0 + r) * 512 + swz(ql, r) * 8], &Ws[(c & ~63) * 8]);
  }
  __syncthreads();
  const int rA = wm * 16 + lr, rB = wn * 16 + lr;
  floatx4 ac[4];
#pragma unroll
  for (int j = 0; j < 4; j++) ac[j] = (floatx4){0.f, 0.f, 0.f, 0.f};
#pragma unroll
  for (int t = 0; t < 4; t++) {
#pragma unroll
    for (int j = 0; j < 4; j++) {
      int q = ((j * 128 + t * 32) >> 3) + lk;
      short8 av = *(const short8*)&As[rA * 512 + swz(q, rA) * 8];
      short8 bv = *(const short8*)&Ws[rB * 512 + swz(q, rB) * 8];
      ac[j] = __builtin_amdgcn_mfma_f32_16x16x32_bf16(av, bv, ac[j], 0, 0, 0);
    }
  }
  floatx4 acc = (ac[0] + ac[1]) + (ac[2] + ac[3]);
  int n = n0 + wn * 16 + lr;
  float bn = bias[n];
  // C/D layout (m89-verified): col = lane&15, row = (lane>>4)*4 + reg
#pragma unroll
  for (int r = 0; r < 4; r++) {
    int m = m0 + wm * 16 + lk * 4 + r;
    C[(size_t)m * 512 + n] = f2bf(elu1(acc[r] + bn));
  }
}

// ---- expert GEMM: 32x32 tile, 8 experts/block, dbuf W; flat 1D grid --------
// blocks 0..511: GEMM (x=id&15 -> n0, y=(id>>4)&15 -> m0, kz=id>>8).
// GATES=1: block computes softmax gates for its 32 rows in-kernel (overlapped
//   with staging); blocks with x==0&&kz==0 publish gates to global for later
//   launches. GATES=0: gates read from global.
// EXTRA=1: blocks 512+ convert fp32->bf16 (alpha bank rider).
// EXTRA=2: blocks 512+ zero-fill zdst (1 MB out rider).
// FROMP: A-panel = elu(Pin[0]+Pin[1]) staged via VALU (fused reduce).
// ATOMIC: epilogue atomicAdds into Pout (pre-zeroed out) instead of writing.
template <int FROMP, int ATOMIC, int GATES, int EXTRA>
__global__ __launch_bounds__(256) void expert_gemm(
    const unsigned short* __restrict__ A,   // [512,512] bf16 (FROMP=0)
    const float* __restrict__ Pin,          // [2][512][512] (FROMP=1)
    const unsigned short* __restrict__ Wb,  // [E*512,512] bf16 alpha bank
    float* __restrict__ gates,              // [512,8]: GATES?write:read
    const float* __restrict__ beta,         // [E*512] fp32
    float* __restrict__ Pout,               // [2][512][512] or out[512][512]
    const unsigned short* __restrict__ G1,  // [B,H] bf16 (GATES=1)
    const float* __restrict__ gw2, const float* __restrict__ gb2,
    const float* __restrict__ xsrc, unsigned short* __restrict__ xdst,
    float* __restrict__ zdst) {
  const int id = blockIdx.x, tid = threadIdx.x;
  if (EXTRA == 1 && id >= 512) {
    cvt_chunk(xsrc, xdst, id - 512, tid);
    return;
  }
  if (EXTRA == 2 && id >= 512) {
    ((float4*)zdst)[(id - 512) * 256 + tid] = (float4){0.f, 0.f, 0.f, 0.f};
    return;
  }
  __shared__ unsigned short As[32 * 256];     // 16 KB
  __shared__ unsigned short Ws[2][32 * 256];  // 2 x 16 KB
  __shared__ float gl[32 * 8];                // 1 KB local gates
  const int wave = tid >> 6, lane = tid & 63;
  const int wm = wave >> 1, wn = wave & 1;
  const int lr = lane & 15, lk = lane >> 4;
  const int xib = id & 15, yib = (id >> 4) & 15, kz = id >> 8;
  const int n0 = xib * 32, m0 = yib * 32, kbeg = kz * 256;

  // stage A panel (32x256): 1024 chunks, 4 per thread
  if (FROMP) {
#pragma unroll
    for (int i = 0; i < 4; i++) {
      int c = tid + i * 256;
      int r = c >> 5, q = c & 31;
      const float* p0 = Pin + (size_t)(m0 + r) * 512 + kbeg + q * 8;
      const float* p1 = p0 + (size_t)Bq * Hq;
      float4 x0 = *(const float4*)p0, x1 = *(const float4*)(p0 + 4);
      float4 y0 = *(const float4*)p1, y1 = *(const float4*)(p1 + 4);
      short8 o;
      o[0] = (short)f2bf(elu1(x0.x + y0.x));
      o[1] = (short)f2bf(elu1(x0.y + y0.y));
      o[2] = (short)f2bf(elu1(x0.z + y0.z));
      o[3] = (short)f2bf(elu1(x0.w + y0.w));
      o[4] = (short)f2bf(elu1(x1.x + y1.x));
      o[5] = (short)f2bf(elu1(x1.y + y1.y));
      o[6] = (short)f2bf(elu1(x1.z + y1.z));
      o[7] = (short)f2bf(elu1(x1.w + y1.w));
      *(short8*)&As[(r * 32 + swz(q, r)) * 8] = o;
    }
  } else {
#pragma unroll
    for (int i = 0; i < 4; i++) {
      int c = tid + i * 256;
      int r = c >> 5, ql = c & 31;
      gld16(&A[(size_t)(m0 + r) * 512 + kbeg + swz(ql, r) * 8],
            &As[(c & ~63) * 8]);
    }
  }
  auto stageW = [&](int e, int b) {
    const unsigned short* Wp = Wb + ((size_t)e * 512 + n0) * 512 + kbeg;
#pragma unroll
    for (int i = 0; i < 4; i++) {
      int c = tid + i * 256;
      int r = c >> 5, ql = c & 31;
      gld16(&Wp[(size_t)r * 512 + swz(ql, r) * 8], &Ws[b][(c & ~63) * 8]);
    }
  };
  stageW(0, 0);

  float g8[4][8];
  if (GATES) {
    // fused softmax: each wave computes 8 of the block's 32 rows (identical
    // per-lane arithmetic to the old gate kernel -> bit-identical gates),
    // overlapped with the in-flight async staging above.
#pragma unroll
    for (int rr = 0; rr < 8; rr++) {
      int row = wave * 8 + rr;
      int m = m0 + row;
      float xv[8];
#pragma unroll
      for (int t = 0; t < 8; t++)
        xv[t] = bf2f(G1[(size_t)m * 512 + t * 64 + lane]);
      float le[8];
#pragma unroll
      for (int e = 0; e < 8; e++) {
        float p = 0.f;
#pragma unroll
        for (int t = 0; t < 8; t++)
          p += xv[t] * gw2[(size_t)e * 512 + t * 64 + lane];
#pragma unroll
        for (int o = 32; o > 0; o >>= 1) p += __shfl_xor(p, o);
        le[e] = p + gb2[e];
      }
      float mm = le[0];
#pragma unroll
      for (int e = 1; e < 8; e++) mm = fmaxf(mm, le[e]);
      float s = 0.f;
#pragma unroll
      for (int e = 0; e < 8; e++) {
        le[e] = __expf(le[e] - mm);
        s += le[e];
      }
      float inv = 1.f / s;
      if (lane == 0) {
#pragma unroll
        for (int e = 0; e < 8; e++) {
          float gv = le[e] * inv;
          gl[row * 8 + e] = gv;
          if (xib == 0 && kz == 0) gates[(size_t)m * 8 + e] = gv;
        }
      }
    }
  } else {
#pragma unroll
    for (int r = 0; r < 4; r++) {
      int m = m0 + wm * 16 + lk * 4 + r;
      float4 ga = *(const float4*)&gates[(size_t)m * 8];
      float4 gb = *(const float4*)&gates[(size_t)m * 8 + 4];
      g8[r][0] = ga.x; g8[r][1] = ga.y; g8[r][2] = ga.z; g8[r][3] = ga.w;
      g8[r][4] = gb.x; g8[r][5] = gb.y; g8[r][6] = gb.z; g8[r][7] = gb.w;
    }
  }

  const int rA = wm * 16 + lr, rB = wn * 16 + lr;
  floatx4 fin = {0.f, 0.f, 0.f, 0.f};
#pragma unroll
  for (int e = 0; e < 8; e++) {
    __syncthreads();                        // A + W[e] ready; fences reuse
    if (e < 7) stageW(e + 1, (e + 1) & 1);  // prefetch overlaps MFMA
    const unsigned short* wb = Ws[e & 1];
    floatx4 c0 = {0.f, 0.f, 0.f, 0.f}, c1 = {0.f, 0.f, 0.f, 0.f};
#pragma unroll
    for (int s = 0; s < 8; s++) {
      int q = s * 4 + lk;
      short8 av = *(const short8*)&As[rA * 256 + swz(q, rA) * 8];
      short8 bv = *(const short8*)&wb[rB * 256 + swz(q, rB) * 8];
      if (s & 1)
        c1 = __builtin_amdgcn_mfma_f32_16x16x32_bf16(av, bv, c1, 0, 0, 0);
      else
        c0 = __builtin_amdgcn_mfma_f32_16x16x32_bf16(av, bv, c0, 0, 0, 0);
    }
    floatx4 ae = c0 + c1;
#pragma unroll
    for (int r = 0; r < 4; r++) {
      float ge = GATES ? gl[(wm * 16 + lk * 4 + r) * 8 + e] : g8[r][e];
      fin[r] += ge * ae[r];
    }
  }

  int n = n0 + wn * 16 + lr;
  if (kz == 0) {  // fold gate-blended beta into the kz=0 partial
    float bv[8];
#pragma unroll
    for (int e = 0; e < 8; e++) bv[e] = beta[e * 512 + n];
#pragma unroll
    for (int r = 0; r < 4; r++) {
      float bs = 0.f;
#pragma unroll
      for (int e = 0; e < 8; e++) {
        float ge = GATES ? gl[(wm * 16 + lk * 4 + r) * 8 + e] : g8[r][e];
        bs += ge * bv[e];
      }
      fin[r] += bs;
    }
  }
  if (ATOMIC) {
#pragma unroll
    for (int r = 0; r < 4; r++) {
      int m = m0 + wm * 16 + lk * 4 + r;
      atomicAdd(&Pout[(size_t)m * 512 + n], fin[r]);
    }
  } else {
    float* Po = Pout + (size_t)kz * Bq * Hq;
#pragma unroll
    for (int r = 0; r < 4; r++) {
      int m = m0 + wm * 16 + lk * 4 + r;
      Po[(size_t)m * 512 + n] = fin[r];
    }
  }
}

extern "C" void kernel_launch(void* const* d_in, const int* in_sizes, int n_in,
                              void* d_out, int out_size, void* d_ws,
                              size_t ws_size, hipStream_t stream) {
  const float* x = (const float*)d_in[0];
  const float* gw0 = (const float*)d_in[1];
  const float* gb0 = (const float*)d_in[2];
  const float* gw1 = (const float*)d_in[3];
  const float* gb1 = (const float*)d_in[4];
  const float* gw2 = (const float*)d_in[5];
  const float* gb2 = (const float*)d_in[6];
  const float* alpha0 = (const float*)d_in[7];
  const float* beta0 = (const float*)d_in[8];
  const float* alpha1 = (const float*)d_in[9];
  const float* beta1 = (const float*)d_in[10];
  const float* alpha2 = (const float*)d_in[11];
  const float* beta2 = (const float*)d_in[12];
  float* out = (float*)d_out;

  char* ws = (char*)d_ws;
  auto alloc = [&](size_t bytes) {
    char* p = ws;
    ws += (bytes + 255) & ~(size_t)255;
    return p;
  };
  unsigned short* xb = (unsigned short*)alloc((size_t)Bq * Fq * 2);
  unsigned short* gw0b = (unsigned short*)alloc((size_t)Hq * Fq * 2);
  unsigned short* gw1b = (unsigned short*)alloc((size_t)Hq * Hq * 2);
  unsigned short* a0b = (unsigned short*)alloc((size_t)Eq * Hq * Fq * 2);
  unsigned short* a1b = (unsigned short*)alloc((size_t)Eq * Hq * Hq * 2);
  unsigned short* a2b = (unsigned short*)alloc((size_t)Eq * Oq * Hq * 2);
  unsigned short* G0b = (unsigned short*)alloc((size_t)Bq * Hq * 2);
  unsigned short* G1b = (unsigned short*)alloc((size_t)Bq * Hq * 2);
  float* gates = (float*)alloc((size_t)Bq * Eq * 4);
  float* P1 = (float*)alloc((size_t)2 * Bq * Hq * 4);
  float* P2 = (float*)alloc((size_t)2 * Bq * Hq * 4);

  // 1) small converts (x, gw0)
  cvt_small2<<<512, 256, 0, stream>>>(x, gw0, xb, gw0b);

  // 2) gating GEMMs; alpha0+gw1 cvt ride L0, alpha1 cvt rides L1
  gating_cvt<<<2560, 256, 0, stream>>>(xb, gw0b, gb0, G0b, alpha0, a0b,
                                       gw1, gw1b);
  gating_cvt<<<2304, 256, 0, stream>>>(G0b, gw1b, gb1, G1b, alpha1, a1b,
                                       nullptr, nullptr);

  // 3) experts; expert1 fuses softmax + publishes gates, alpha2 cvt rides it;
  //    out-zeroing rides expert2; expert3 atomically accumulates into out.
  expert_gemm<0, 0, 1, 1><<<2560, 256, 0, stream>>>(
      xb, nullptr, a0b, gates, beta0, P1, G1b, gw2, gb2, alpha2, a2b, nullptr);
  expert_gemm<1, 0, 0, 2><<<768, 256, 0, stream>>>(
      nullptr, P1, a1b, gates, beta1, P2, nullptr, nullptr, nullptr, nullptr,
      nullptr, out);
  expert_gemm<1, 1, 0, 0><<<512, 256, 0, stream>>>(
      nullptr, P2, a2b, gates, beta2, out, nullptr, nullptr, nullptr, nullptr,
      nullptr, nullptr);
}

// Round 12
// 135.627 us; speedup vs baseline: 1.2050x; 1.2050x over previous
//
#include <hip/hip_runtime.h>
#include <hip/hip_bf16.h>
#include <math.h>

// Problem constants (B,F,H,E,O) = (512,512,512,8,512)
enum { Bq = 512, Fq = 512, Hq = 512, Eq = 8, Oq = 512 };

typedef __attribute__((ext_vector_type(8))) short short8;
typedef __attribute__((ext_vector_type(4))) float floatx4;

static __device__ __forceinline__ unsigned short f2bf(float f) {
  unsigned u = __float_as_uint(f);
  u += 0x7fffu + ((u >> 16) & 1u);
  return (unsigned short)(u >> 16);
}
static __device__ __forceinline__ float bf2f(unsigned short h) {
  return __uint_as_float(((unsigned)h) << 16);
}
static __device__ __forceinline__ float elu1(float v) {
  return v > 0.f ? v : (__expf(v) - 1.f);
}

// async global->LDS 16B copy (wave-uniform LDS base + lane*16 scatter)
typedef __attribute__((address_space(1))) const unsigned int gu32;
typedef __attribute__((address_space(3))) unsigned int lu32;
static __device__ __forceinline__ void gld16(const unsigned short* g,
                                             unsigned short* l) {
  __builtin_amdgcn_global_load_lds((gu32*)g, (lu32*)l, 16, 0, 0);
}

// XOR swizzle on 16B chunks (fragment-read conflicts -> 2-way = free).
static __device__ __forceinline__ int swz(int q, int r) {
  return (q & ~7) | ((q ^ r) & 7);
}

// one 256-thread block converts 256 float4 (1024 elems) fp32->bf16
static __device__ __forceinline__ void cvt_chunk(const float* __restrict__ src,
                                                 unsigned short* __restrict__ dst,
                                                 int chunk, int tid) {
  int j = chunk * 256 + tid;
  float4 v = ((const float4*)src)[j];
  ushort4 o;
  o.x = f2bf(v.x); o.y = f2bf(v.y); o.z = f2bf(v.z); o.w = f2bf(v.w);
  *(ushort4*)(dst + 4 * (size_t)j) = o;
}

// load 8 fp32 -> bf16x8
static __device__ __forceinline__ short8 cvt8(const float* __restrict__ p) {
  float4 v0 = *(const float4*)p, v1 = *(const float4*)(p + 4);
  short8 o;
  o[0] = (short)f2bf(v0.x); o[1] = (short)f2bf(v0.y);
  o[2] = (short)f2bf(v0.z); o[3] = (short)f2bf(v0.w);
  o[4] = (short)f2bf(v1.x); o[5] = (short)f2bf(v1.y);
  o[6] = (short)f2bf(v1.z); o[7] = (short)f2bf(v1.w);
  return o;
}

// --- gating GEMM (blocks 0..255) + alpha cvt rider (256..2303) --------------
// F32A / F32W: stage that panel from fp32 via VALU cvt (else gld16 from bf16).
// 32x32 tile, BK=512 (full K), one barrier, 64 KB LDS -> 2 blocks/CU.
template <int F32A, int F32W>
__global__ __launch_bounds__(256) void gating_cvt(
    const unsigned short* __restrict__ A, const float* __restrict__ Af,
    const unsigned short* __restrict__ W, const float* __restrict__ Wf,
    const float* __restrict__ bias, unsigned short* __restrict__ C,
    const float* __restrict__ asrc, unsigned short* __restrict__ adst) {
  const int blk = blockIdx.x, tid = threadIdx.x;
  if (blk >= 256) {
    cvt_chunk(asrc, adst, blk - 256, tid);
    return;
  }
  __shared__ unsigned short As[32 * 512];
  __shared__ unsigned short Ws[32 * 512];
  const int wave = tid >> 6, lane = tid & 63;
  const int wm = wave >> 1, wn = wave & 1;
  const int lr = lane & 15, lk = lane >> 4;
  const int m0 = (blk >> 4) * 32, n0 = (blk & 15) * 32;
#pragma unroll
  for (int i = 0; i < 8; i++) {
    int c = tid + i * 256;
    int r = c >> 6, q = c & 63;
    if (F32A) {
      *(short8*)&As[(r * 64 + swz(q, r)) * 8] =
          cvt8(Af + (size_t)(m0 + r) * 512 + q * 8);
    } else {
      gld16(&A[(size_t)(m0 + r) * 512 + swz(q, r) * 8], &As[(c & ~63) * 8]);
    }
  }
#pragma unroll
  for (int i = 0; i < 8; i++) {
    int c = tid + i * 256;
    int r = c >> 6, q = c & 63;
    if (F32W) {
      *(short8*)&Ws[(r * 64 + swz(q, r)) * 8] =
          cvt8(Wf + (size_t)(n0 + r) * 512 + q * 8);
    } else {
      gld16(&W[(size_t)(n0 + r) * 512 + swz(q, r) * 8], &Ws[(c & ~63) * 8]);
    }
  }
  __syncthreads();
  const int rA = wm * 16 + lr, rB = wn * 16 + lr;
  floatx4 ac[4];
#pragma unroll
  for (int j = 0; j < 4; j++) ac[j] = (floatx4){0.f, 0.f, 0.f, 0.f};
#pragma unroll
  for (int t = 0; t < 4; t++) {
#pragma unroll
    for (int j = 0; j < 4; j++) {
      int q = ((j * 128 + t * 32) >> 3) + lk;
      short8 av = *(const short8*)&As[rA * 512 + swz(q, rA) * 8];
      short8 bv = *(const short8*)&Ws[rB * 512 + swz(q, rB) * 8];
      ac[j] = __builtin_amdgcn_mfma_f32_16x16x32_bf16(av, bv, ac[j], 0, 0, 0);
    }
  }
  floatx4 acc = (ac[0] + ac[1]) + (ac[2] + ac[3]);
  int n = n0 + wn * 16 + lr;
  float bn = bias[n];
  // C/D layout (m89-verified): col = lane&15, row = (lane>>4)*4 + reg
#pragma unroll
  for (int r = 0; r < 4; r++) {
    int m = m0 + wm * 16 + lk * 4 + r;
    C[(size_t)m * 512 + n] = f2bf(elu1(acc[r] + bn));
  }
}

// --- gate softmax (blocks 0..127, 4 samples/block) + out-zero (128..383)
//     + alpha2 cvt (blocks 384..2431) ---------------------------------------
__global__ __launch_bounds__(256) void gate_fused(
    const unsigned short* __restrict__ G1,  // [B,H] bf16
    const float* __restrict__ gw2,          // [E,H]
    const float* __restrict__ gb2,          // [E]
    float* __restrict__ g,                  // [B,E]
    const float* __restrict__ asrc, unsigned short* __restrict__ adst,
    float* __restrict__ outz) {
  const int blk = blockIdx.x, tid = threadIdx.x;
  if (blk >= 384) {
    cvt_chunk(asrc, adst, blk - 384, tid);
    return;
  }
  if (blk >= 128) {
    ((float4*)outz)[(blk - 128) * 256 + tid] = (float4){0.f, 0.f, 0.f, 0.f};
    return;
  }
  const int wave = tid >> 6, lane = tid & 63;
  const int b = blk * 4 + wave;
  float xv[8];
#pragma unroll
  for (int t = 0; t < 8; t++) xv[t] = bf2f(G1[(size_t)b * Hq + t * 64 + lane]);
  float le[Eq];
#pragma unroll
  for (int e = 0; e < Eq; e++) {
    float p = 0.f;
#pragma unroll
    for (int t = 0; t < 8; t++)
      p += xv[t] * gw2[(size_t)e * Hq + t * 64 + lane];
#pragma unroll
    for (int o = 32; o > 0; o >>= 1) p += __shfl_xor(p, o);
    le[e] = p + gb2[e];
  }
  float m = le[0];
#pragma unroll
  for (int e = 1; e < Eq; e++) m = fmaxf(m, le[e]);
  float s = 0.f;
#pragma unroll
  for (int e = 0; e < Eq; e++) {
    le[e] = __expf(le[e] - m);
    s += le[e];
  }
  float inv = 1.f / s;
  if (lane == 0) {
#pragma unroll
    for (int e = 0; e < Eq; e++) g[(size_t)b * Eq + e] = le[e] * inv;
  }
}

// ---- expert GEMM (R7/R10 shape): 32x32 tile, 8 experts/block, dbuf W -------
// grid (16 n, 16 m, 2 kz) = 512 blocks, 48 KB LDS -> 3 blocks/CU.
// FROMX: A-panel staged from fp32 x via VALU cvt.
// FROMP: A-panel = elu(Pin[0]+Pin[1]) staged via VALU (fused reduce).
// ATOMIC: epilogue atomicAdds into pre-zeroed out instead of writing Pout.
template <int FROMX, int FROMP, int ATOMIC>
__global__ __launch_bounds__(256) void expert_gemm(
    const float* __restrict__ Xf,           // [512,512] fp32 (FROMX=1)
    const float* __restrict__ Pin,          // [2][512][512] (FROMP=1)
    const unsigned short* __restrict__ Wb,  // [E*512,512] bf16 alpha bank
    const float* __restrict__ g,            // [512,8] gates
    const float* __restrict__ beta,         // [E*512] fp32
    float* __restrict__ Pout) {             // [2][512][512] or out[512][512]
  __shared__ unsigned short As[32 * 256];     // 16 KB
  __shared__ unsigned short Ws[2][32 * 256];  // 2 x 16 KB
  const int tid = threadIdx.x;
  const int wave = tid >> 6, lane = tid & 63;
  const int wm = wave >> 1, wn = wave & 1;
  const int lr = lane & 15, lk = lane >> 4;
  const int m0 = blockIdx.y * 32, n0 = blockIdx.x * 32;
  const int kz = blockIdx.z, kbeg = kz * 256;

  // stage A panel (32x256): 1024 chunks, 4 per thread
  if (FROMP) {
#pragma unroll
    for (int i = 0; i < 4; i++) {
      int c = tid + i * 256;
      int r = c >> 5, q = c & 31;
      const float* p0 = Pin + (size_t)(m0 + r) * 512 + kbeg + q * 8;
      const float* p1 = p0 + (size_t)Bq * Hq;
      float4 x0 = *(const float4*)p0, x1 = *(const float4*)(p0 + 4);
      float4 y0 = *(const float4*)p1, y1 = *(const float4*)(p1 + 4);
      short8 o;
      o[0] = (short)f2bf(elu1(x0.x + y0.x));
      o[1] = (short)f2bf(elu1(x0.y + y0.y));
      o[2] = (short)f2bf(elu1(x0.z + y0.z));
      o[3] = (short)f2bf(elu1(x0.w + y0.w));
      o[4] = (short)f2bf(elu1(x1.x + y1.x));
      o[5] = (short)f2bf(elu1(x1.y + y1.y));
      o[6] = (short)f2bf(elu1(x1.z + y1.z));
      o[7] = (short)f2bf(elu1(x1.w + y1.w));
      *(short8*)&As[(r * 32 + swz(q, r)) * 8] = o;
    }
  } else if (FROMX) {
#pragma unroll
    for (int i = 0; i < 4; i++) {
      int c = tid + i * 256;
      int r = c >> 5, q = c & 31;
      *(short8*)&As[(r * 32 + swz(q, r)) * 8] =
          cvt8(Xf + (size_t)(m0 + r) * 512 + kbeg + q * 8);
    }
  }
  // stage W panel for expert 0 into buffer 0
  auto stageW = [&](int e, int b) {
    const unsigned short* Wp = Wb + ((size_t)e * 512 + n0) * 512 + kbeg;
#pragma unroll
    for (int i = 0; i < 4; i++) {
      int c = tid + i * 256;
      int r = c >> 5, ql = c & 31;
      gld16(&Wp[(size_t)r * 512 + swz(ql, r) * 8], &Ws[b][(c & ~63) * 8]);
    }
  };
  stageW(0, 0);
  // gates for this lane's 4 output rows
  float g8[4][8];
#pragma unroll
  for (int r = 0; r < 4; r++) {
    int m = m0 + wm * 16 + lk * 4 + r;
    float4 ga = *(const float4*)&g[(size_t)m * 8];
    float4 gb = *(const float4*)&g[(size_t)m * 8 + 4];
    g8[r][0] = ga.x; g8[r][1] = ga.y; g8[r][2] = ga.z; g8[r][3] = ga.w;
    g8[r][4] = gb.x; g8[r][5] = gb.y; g8[r][6] = gb.z; g8[r][7] = gb.w;
  }

  const int rA = wm * 16 + lr, rB = wn * 16 + lr;
  floatx4 fin = {0.f, 0.f, 0.f, 0.f};
#pragma unroll
  for (int e = 0; e < 8; e++) {
    __syncthreads();                        // A + W[e] ready; fences reuse
    if (e < 7) stageW(e + 1, (e + 1) & 1);  // prefetch overlaps MFMA
    const unsigned short* wb = Ws[e & 1];
    floatx4 c0 = {0.f, 0.f, 0.f, 0.f}, c1 = {0.f, 0.f, 0.f, 0.f};
#pragma unroll
    for (int s = 0; s < 8; s++) {
      int q = s * 4 + lk;
      short8 av = *(const short8*)&As[rA * 256 + swz(q, rA) * 8];
      short8 bv = *(const short8*)&wb[rB * 256 + swz(q, rB) * 8];
      if (s & 1)
        c1 = __builtin_amdgcn_mfma_f32_16x16x32_bf16(av, bv, c1, 0, 0, 0);
      else
        c0 = __builtin_amdgcn_mfma_f32_16x16x32_bf16(av, bv, c0, 0, 0, 0);
    }
    floatx4 ae = c0 + c1;
#pragma unroll
    for (int r = 0; r < 4; r++) fin[r] += g8[r][e] * ae[r];
  }

  int n = n0 + wn * 16 + lr;
  if (kz == 0) {  // fold gate-blended beta into the kz=0 partial
    float bv[8];
#pragma unroll
    for (int e = 0; e < 8; e++) bv[e] = beta[e * 512 + n];
#pragma unroll
    for (int r = 0; r < 4; r++) {
      float bs = 0.f;
#pragma unroll
      for (int e = 0; e < 8; e++) bs += g8[r][e] * bv[e];
      fin[r] += bs;
    }
  }
  if (ATOMIC) {
#pragma unroll
    for (int r = 0; r < 4; r++) {
      int m = m0 + wm * 16 + lk * 4 + r;
      atomicAdd(&Pout[(size_t)m * 512 + n], fin[r]);
    }
  } else {
    float* Po = Pout + (size_t)kz * Bq * Hq;
#pragma unroll
    for (int r = 0; r < 4; r++) {
      int m = m0 + wm * 16 + lk * 4 + r;
      Po[(size_t)m * 512 + n] = fin[r];
    }
  }
}

extern "C" void kernel_launch(void* const* d_in, const int* in_sizes, int n_in,
                              void* d_out, int out_size, void* d_ws,
                              size_t ws_size, hipStream_t stream) {
  const float* x = (const float*)d_in[0];
  const float* gw0 = (const float*)d_in[1];
  const float* gb0 = (const float*)d_in[2];
  const float* gw1 = (const float*)d_in[3];
  const float* gb1 = (const float*)d_in[4];
  const float* gw2 = (const float*)d_in[5];
  const float* gb2 = (const float*)d_in[6];
  const float* alpha0 = (const float*)d_in[7];
  const float* beta0 = (const float*)d_in[8];
  const float* alpha1 = (const float*)d_in[9];
  const float* beta1 = (const float*)d_in[10];
  const float* alpha2 = (const float*)d_in[11];
  const float* beta2 = (const float*)d_in[12];
  float* out = (float*)d_out;

  char* ws = (char*)d_ws;
  auto alloc = [&](size_t bytes) {
    char* p = ws;
    ws += (bytes + 255) & ~(size_t)255;
    return p;
  };
  unsigned short* a0b = (unsigned short*)alloc((size_t)Eq * Hq * Fq * 2);
  unsigned short* a1b = (unsigned short*)alloc((size_t)Eq * Hq * Hq * 2);
  unsigned short* a2b = (unsigned short*)alloc((size_t)Eq * Oq * Hq * 2);
  unsigned short* G0b = (unsigned short*)alloc((size_t)Bq * Hq * 2);
  unsigned short* G1b = (unsigned short*)alloc((size_t)Bq * Hq * 2);
  float* gates = (float*)alloc((size_t)Bq * Eq * 4);
  float* P1 = (float*)alloc((size_t)2 * Bq * Hq * 4);
  float* P2 = (float*)alloc((size_t)2 * Bq * Hq * 4);

  // 1) gating L0: A,W VALU-staged from fp32 x/gw0; alpha0 cvt rides
  gating_cvt<1, 1><<<2304, 256, 0, stream>>>(nullptr, x, nullptr, gw0, gb0,
                                             G0b, alpha0, a0b);
  // 2) gating L1: A from bf16 G0b, W VALU-staged from fp32 gw1; alpha1 rides
  gating_cvt<0, 1><<<2304, 256, 0, stream>>>(G0b, nullptr, nullptr, gw1, gb1,
                                             G1b, alpha1, a1b);
  // 3) gate softmax + out zero-init + alpha2 cvt
  gate_fused<<<2432, 256, 0, stream>>>(G1b, gw2, gb2, gates, alpha2, a2b, out);

  // 4) experts; layer1 stages A from fp32 x; layer3 atomically adds into out
  dim3 ge(16, 16, 2);
  expert_gemm<1, 0, 0><<<ge, 256, 0, stream>>>(x, nullptr, a0b, gates, beta0,
                                               P1);
  expert_gemm<0, 1, 0><<<ge, 256, 0, stream>>>(nullptr, P1, a1b, gates, beta1,
                                               P2);
  expert_gemm<0, 1, 1><<<ge, 256, 0, stream>>>(nullptr, P2, a2b, gates, beta2,
                                               out);
}

// Round 13
// 135.486 us; speedup vs baseline: 1.2063x; 1.0010x over previous
//
#include <hip/hip_runtime.h>
#include <hip/hip_bf16.h>
#include <math.h>

// Problem constants (B,F,H,E,O) = (512,512,512,8,512)
enum { Bq = 512, Fq = 512, Hq = 512, Eq = 8, Oq = 512 };

typedef __attribute__((ext_vector_type(8))) short short8;
typedef __attribute__((ext_vector_type(4))) float floatx4;

static __device__ __forceinline__ unsigned short f2bf(float f) {
  unsigned u = __float_as_uint(f);
  u += 0x7fffu + ((u >> 16) & 1u);
  return (unsigned short)(u >> 16);
}
static __device__ __forceinline__ float bf2f(unsigned short h) {
  return __uint_as_float(((unsigned)h) << 16);
}
static __device__ __forceinline__ float elu1(float v) {
  return v > 0.f ? v : (__expf(v) - 1.f);
}

// async global->LDS 16B copy (wave-uniform LDS base + lane*16 scatter)
typedef __attribute__((address_space(1))) const unsigned int gu32;
typedef __attribute__((address_space(3))) unsigned int lu32;
static __device__ __forceinline__ void gld16(const unsigned short* g,
                                             unsigned short* l) {
  __builtin_amdgcn_global_load_lds((gu32*)g, (lu32*)l, 16, 0, 0);
}

// XOR swizzle on 16B chunks (fragment-read conflicts -> 2-way = free).
static __device__ __forceinline__ int swz(int q, int r) {
  return (q & ~7) | ((q ^ r) & 7);
}

// one 256-thread block converts 256 float4 (1024 elems) fp32->bf16
static __device__ __forceinline__ void cvt_chunk(const float* __restrict__ src,
                                                 unsigned short* __restrict__ dst,
                                                 int chunk, int tid) {
  int j = chunk * 256 + tid;
  float4 v = ((const float4*)src)[j];
  ushort4 o;
  o.x = f2bf(v.x); o.y = f2bf(v.y); o.z = f2bf(v.z); o.w = f2bf(v.w);
  *(ushort4*)(dst + 4 * (size_t)j) = o;
}

// load 8 fp32 -> bf16x8
static __device__ __forceinline__ short8 cvt8(const float* __restrict__ p) {
  float4 v0 = *(const float4*)p, v1 = *(const float4*)(p + 4);
  short8 o;
  o[0] = (short)f2bf(v0.x); o[1] = (short)f2bf(v0.y);
  o[2] = (short)f2bf(v0.z); o[3] = (short)f2bf(v0.w);
  o[4] = (short)f2bf(v1.x); o[5] = (short)f2bf(v1.y);
  o[6] = (short)f2bf(v1.z); o[7] = (short)f2bf(v1.w);
  return o;
}

// --- gating GEMM (blocks 0..255) + alpha cvt rider (256..2303) --------------
// F32A / F32W: stage that panel from fp32 via VALU cvt (else gld16 from bf16).
// 32x32 tile, BK=512 (full K), one barrier, 64 KB LDS -> 2 blocks/CU.
template <int F32A, int F32W>
__global__ __launch_bounds__(256) void gating_cvt(
    const unsigned short* __restrict__ A, const float* __restrict__ Af,
    const unsigned short* __restrict__ W, const float* __restrict__ Wf,
    const float* __restrict__ bias, unsigned short* __restrict__ C,
    const float* __restrict__ asrc, unsigned short* __restrict__ adst) {
  const int blk = blockIdx.x, tid = threadIdx.x;
  if (blk >= 256) {
    cvt_chunk(asrc, adst, blk - 256, tid);
    return;
  }
  __shared__ unsigned short As[32 * 512];
  __shared__ unsigned short Ws[32 * 512];
  const int wave = tid >> 6, lane = tid & 63;
  const int wm = wave >> 1, wn = wave & 1;
  const int lr = lane & 15, lk = lane >> 4;
  const int m0 = (blk >> 4) * 32, n0 = (blk & 15) * 32;
#pragma unroll
  for (int i = 0; i < 8; i++) {
    int c = tid + i * 256;
    int r = c >> 6, q = c & 63;
    if (F32A) {
      *(short8*)&As[(r * 64 + swz(q, r)) * 8] =
          cvt8(Af + (size_t)(m0 + r) * 512 + q * 8);
    } else {
      gld16(&A[(size_t)(m0 + r) * 512 + swz(q, r) * 8], &As[(c & ~63) * 8]);
    }
  }
#pragma unroll
  for (int i = 0; i < 8; i++) {
    int c = tid + i * 256;
    int r = c >> 6, q = c & 63;
    if (F32W) {
      *(short8*)&Ws[(r * 64 + swz(q, r)) * 8] =
          cvt8(Wf + (size_t)(n0 + r) * 512 + q * 8);
    } else {
      gld16(&W[(size_t)(n0 + r) * 512 + swz(q, r) * 8], &Ws[(c & ~63) * 8]);
    }
  }
  __syncthreads();
  const int rA = wm * 16 + lr, rB = wn * 16 + lr;
  floatx4 ac[4];
#pragma unroll
  for (int j = 0; j < 4; j++) ac[j] = (floatx4){0.f, 0.f, 0.f, 0.f};
#pragma unroll
  for (int t = 0; t < 4; t++) {
#pragma unroll
    for (int j = 0; j < 4; j++) {
      int q = ((j * 128 + t * 32) >> 3) + lk;
      short8 av = *(const short8*)&As[rA * 512 + swz(q, rA) * 8];
      short8 bv = *(const short8*)&Ws[rB * 512 + swz(q, rB) * 8];
      ac[j] = __builtin_amdgcn_mfma_f32_16x16x32_bf16(av, bv, ac[j], 0, 0, 0);
    }
  }
  floatx4 acc = (ac[0] + ac[1]) + (ac[2] + ac[3]);
  int n = n0 + wn * 16 + lr;
  float bn = bias[n];
  // C/D layout (m89-verified): col = lane&15, row = (lane>>4)*4 + reg
#pragma unroll
  for (int r = 0; r < 4; r++) {
    int m = m0 + wm * 16 + lk * 4 + r;
    C[(size_t)m * 512 + n] = f2bf(elu1(acc[r] + bn));
  }
}

// --- gate softmax (blocks 0..127, 4 samples/block) + out-zero (128..383)
//     + alpha2 cvt (blocks 384..2431) ---------------------------------------
__global__ __launch_bounds__(256) void gate_fused(
    const unsigned short* __restrict__ G1,  // [B,H] bf16
    const float* __restrict__ gw2,          // [E,H]
    const float* __restrict__ gb2,          // [E]
    float* __restrict__ g,                  // [B,E]
    const float* __restrict__ asrc, unsigned short* __restrict__ adst,
    float* __restrict__ outz) {
  const int blk = blockIdx.x, tid = threadIdx.x;
  if (blk >= 384) {
    cvt_chunk(asrc, adst, blk - 384, tid);
    return;
  }
  if (blk >= 128) {
    ((float4*)outz)[(blk - 128) * 256 + tid] = (float4){0.f, 0.f, 0.f, 0.f};
    return;
  }
  const int wave = tid >> 6, lane = tid & 63;
  const int b = blk * 4 + wave;
  float xv[8];
#pragma unroll
  for (int t = 0; t < 8; t++) xv[t] = bf2f(G1[(size_t)b * Hq + t * 64 + lane]);
  float le[Eq];
#pragma unroll
  for (int e = 0; e < Eq; e++) {
    float p = 0.f;
#pragma unroll
    for (int t = 0; t < 8; t++)
      p += xv[t] * gw2[(size_t)e * Hq + t * 64 + lane];
#pragma unroll
    for (int o = 32; o > 0; o >>= 1) p += __shfl_xor(p, o);
    le[e] = p + gb2[e];
  }
  float m = le[0];
#pragma unroll
  for (int e = 1; e < Eq; e++) m = fmaxf(m, le[e]);
  float s = 0.f;
#pragma unroll
  for (int e = 0; e < Eq; e++) {
    le[e] = __expf(le[e] - m);
    s += le[e];
  }
  float inv = 1.f / s;
  if (lane == 0) {
#pragma unroll
    for (int e = 0; e < Eq; e++) g[(size_t)b * Eq + e] = le[e] * inv;
  }
}

// ---- expert GEMM: 32x32 tile, 8 experts/block, dbuf W, A-frag hoist --------
// grid (16 n, 16 m, 2 kz) = 512 blocks, 48 KB LDS -> 3 blocks/CU.
// A-fragments are invariant across the 8 experts: loaded to registers once at
// e==0 -> in-loop LDS reads are B-only (8 ds_read_b128 feed 16 MFMAs).
// FROMX: A-panel staged from fp32 x via VALU cvt.
// FROMP: A-panel = elu(Pin[0]+Pin[1]) staged via VALU (fused reduce).
// ATOMIC: epilogue atomicAdds into pre-zeroed out instead of writing Pout.
template <int FROMX, int FROMP, int ATOMIC>
__global__ __launch_bounds__(256) void expert_gemm(
    const float* __restrict__ Xf,           // [512,512] fp32 (FROMX=1)
    const float* __restrict__ Pin,          // [2][512][512] (FROMP=1)
    const unsigned short* __restrict__ Wb,  // [E*512,512] bf16 alpha bank
    const float* __restrict__ g,            // [512,8] gates
    const float* __restrict__ beta,         // [E*512] fp32
    float* __restrict__ Pout) {             // [2][512][512] or out[512][512]
  __shared__ unsigned short As[32 * 256];     // 16 KB
  __shared__ unsigned short Ws[2][32 * 256];  // 2 x 16 KB
  const int tid = threadIdx.x;
  const int wave = tid >> 6, lane = tid & 63;
  const int wm = wave >> 1, wn = wave & 1;
  const int lr = lane & 15, lk = lane >> 4;
  const int m0 = blockIdx.y * 32, n0 = blockIdx.x * 32;
  const int kz = blockIdx.z, kbeg = kz * 256;

  // stage A panel (32x256): 1024 chunks, 4 per thread
  if (FROMP) {
#pragma unroll
    for (int i = 0; i < 4; i++) {
      int c = tid + i * 256;
      int r = c >> 5, q = c & 31;
      const float* p0 = Pin + (size_t)(m0 + r) * 512 + kbeg + q * 8;
      const float* p1 = p0 + (size_t)Bq * Hq;
      float4 x0 = *(const float4*)p0, x1 = *(const float4*)(p0 + 4);
      float4 y0 = *(const float4*)p1, y1 = *(const float4*)(p1 + 4);
      short8 o;
      o[0] = (short)f2bf(elu1(x0.x + y0.x));
      o[1] = (short)f2bf(elu1(x0.y + y0.y));
      o[2] = (short)f2bf(elu1(x0.z + y0.z));
      o[3] = (short)f2bf(elu1(x0.w + y0.w));
      o[4] = (short)f2bf(elu1(x1.x + y1.x));
      o[5] = (short)f2bf(elu1(x1.y + y1.y));
      o[6] = (short)f2bf(elu1(x1.z + y1.z));
      o[7] = (short)f2bf(elu1(x1.w + y1.w));
      *(short8*)&As[(r * 32 + swz(q, r)) * 8] = o;
    }
  } else if (FROMX) {
#pragma unroll
    for (int i = 0; i < 4; i++) {
      int c = tid + i * 256;
      int r = c >> 5, q = c & 31;
      *(short8*)&As[(r * 32 + swz(q, r)) * 8] =
          cvt8(Xf + (size_t)(m0 + r) * 512 + kbeg + q * 8);
    }
  }
  // stage W panel for expert 0 into buffer 0
  auto stageW = [&](int e, int b) {
    const unsigned short* Wp = Wb + ((size_t)e * 512 + n0) * 512 + kbeg;
#pragma unroll
    for (int i = 0; i < 4; i++) {
      int c = tid + i * 256;
      int r = c >> 5, ql = c & 31;
      gld16(&Wp[(size_t)r * 512 + swz(ql, r) * 8], &Ws[b][(c & ~63) * 8]);
    }
  };
  stageW(0, 0);
  // gates for this lane's 4 output rows
  float g8[4][8];
#pragma unroll
  for (int r = 0; r < 4; r++) {
    int m = m0 + wm * 16 + lk * 4 + r;
    float4 ga = *(const float4*)&g[(size_t)m * 8];
    float4 gb = *(const float4*)&g[(size_t)m * 8 + 4];
    g8[r][0] = ga.x; g8[r][1] = ga.y; g8[r][2] = ga.z; g8[r][3] = ga.w;
    g8[r][4] = gb.x; g8[r][5] = gb.y; g8[r][6] = gb.z; g8[r][7] = gb.w;
  }

  const int rA = wm * 16 + lr, rB = wn * 16 + lr;
  short8 af[8];  // A fragments, hoisted once at e==0 (invariant over experts)
  floatx4 fin = {0.f, 0.f, 0.f, 0.f};
#pragma unroll
  for (int e = 0; e < 8; e++) {
    __syncthreads();                        // A + W[e] ready; fences reuse
    if (e < 7) stageW(e + 1, (e + 1) & 1);  // prefetch overlaps MFMA
    if (e == 0) {
#pragma unroll
      for (int s = 0; s < 8; s++)
        af[s] = *(const short8*)&As[rA * 256 + swz(s * 4 + lk, rA) * 8];
    }
    const unsigned short* wb = Ws[e & 1];
    floatx4 c0 = {0.f, 0.f, 0.f, 0.f}, c1 = {0.f, 0.f, 0.f, 0.f};
#pragma unroll
    for (int s = 0; s < 8; s++) {
      short8 bv = *(const short8*)&wb[rB * 256 + swz(s * 4 + lk, rB) * 8];
      if (s & 1)
        c1 = __builtin_amdgcn_mfma_f32_16x16x32_bf16(af[s], bv, c1, 0, 0, 0);
      else
        c0 = __builtin_amdgcn_mfma_f32_16x16x32_bf16(af[s], bv, c0, 0, 0, 0);
    }
    floatx4 ae = c0 + c1;
#pragma unroll
    for (int r = 0; r < 4; r++) fin[r] += g8[r][e] * ae[r];
  }

  int n = n0 + wn * 16 + lr;
  if (kz == 0) {  // fold gate-blended beta into the kz=0 partial
    float bv[8];
#pragma unroll
    for (int e = 0; e < 8; e++) bv[e] = beta[e * 512 + n];
#pragma unroll
    for (int r = 0; r < 4; r++) {
      float bs = 0.f;
#pragma unroll
      for (int e = 0; e < 8; e++) bs += g8[r][e] * bv[e];
      fin[r] += bs;
    }
  }
  if (ATOMIC) {
#pragma unroll
    for (int r = 0; r < 4; r++) {
      int m = m0 + wm * 16 + lk * 4 + r;
      atomicAdd(&Pout[(size_t)m * 512 + n], fin[r]);
    }
  } else {
    float* Po = Pout + (size_t)kz * Bq * Hq;
#pragma unroll
    for (int r = 0; r < 4; r++) {
      int m = m0 + wm * 16 + lk * 4 + r;
      Po[(size_t)m * 512 + n] = fin[r];
    }
  }
}

extern "C" void kernel_launch(void* const* d_in, const int* in_sizes, int n_in,
                              void* d_out, int out_size, void* d_ws,
                              size_t ws_size, hipStream_t stream) {
  const float* x = (const float*)d_in[0];
  const float* gw0 = (const float*)d_in[1];
  const float* gb0 = (const float*)d_in[2];
  const float* gw1 = (const float*)d_in[3];
  const float* gb1 = (const float*)d_in[4];
  const float* gw2 = (const float*)d_in[5];
  const float* gb2 = (const float*)d_in[6];
  const float* alpha0 = (const float*)d_in[7];
  const float* beta0 = (const float*)d_in[8];
  const float* alpha1 = (const float*)d_in[9];
  const float* beta1 = (const float*)d_in[10];
  const float* alpha2 = (const float*)d_in[11];
  const float* beta2 = (const float*)d_in[12];
  float* out = (float*)d_out;

  char* ws = (char*)d_ws;
  auto alloc = [&](size_t bytes) {
    char* p = ws;
    ws += (bytes + 255) & ~(size_t)255;
    return p;
  };
  unsigned short* a0b = (unsigned short*)alloc((size_t)Eq * Hq * Fq * 2);
  unsigned short* a1b = (unsigned short*)alloc((size_t)Eq * Hq * Hq * 2);
  unsigned short* a2b = (unsigned short*)alloc((size_t)Eq * Oq * Hq * 2);
  unsigned short* G0b = (unsigned short*)alloc((size_t)Bq * Hq * 2);
  unsigned short* G1b = (unsigned short*)alloc((size_t)Bq * Hq * 2);
  float* gates = (float*)alloc((size_t)Bq * Eq * 4);
  float* P1 = (float*)alloc((size_t)2 * Bq * Hq * 4);
  float* P2 = (float*)alloc((size_t)2 * Bq * Hq * 4);

  // 1) gating L0: A,W VALU-staged from fp32 x/gw0; alpha0 cvt rides
  gating_cvt<1, 1><<<2304, 256, 0, stream>>>(nullptr, x, nullptr, gw0, gb0,
                                             G0b, alpha0, a0b);
  // 2) gating L1: A from bf16 G0b, W VALU-staged from fp32 gw1; alpha1 rides
  gating_cvt<0, 1><<<2304, 256, 0, stream>>>(G0b, nullptr, nullptr, gw1, gb1,
                                             G1b, alpha1, a1b);
  // 3) gate softmax + out zero-init + alpha2 cvt
  gate_fused<<<2432, 256, 0, stream>>>(G1b, gw2, gb2, gates, alpha2, a2b, out);

  // 4) experts; layer1 stages A from fp32 x; layer3 atomically adds into out
  dim3 ge(16, 16, 2);
  expert_gemm<1, 0, 0><<<ge, 256, 0, stream>>>(x, nullptr, a0b, gates, beta0,
                                               P1);
  expert_gemm<0, 1, 0><<<ge, 256, 0, stream>>>(nullptr, P1, a1b, gates, beta1,
                                               P2);
  expert_gemm<0, 1, 1><<<ge, 256, 0, stream>>>(nullptr, P2, a2b, gates, beta2,
                                               out);
}